// Round 1
// baseline (102.241 us; speedup 1.0000x reference)
//
#include <hip/hip_runtime.h>

// DynamicPatcher: out = [patch_lengths (B,P) int32 | patch_ids (B,S) int32] flat.
// Input entropy is used only for its shape -> pure store kernel, ~67 MB writes.
//
// Closed form (host-side): avg = max(S/P,1); nf = #leading patches of size avg;
// lengths[p<nf]=avg, lengths[nf]=breakRem (if break), lengths[P-1]=lastVal;
// patch_ids[pos] = min(pos/avg, nf).
//
// Layout: gridDim.y = row (batch). x-blocks [0, blocksPerRow) write patch_ids
// (each thread: 4 x int4 = 64 B, fully coalesced). x-block == blocksPerRow
// writes the row's patch_lengths. avg pow2 -> shift; else u32 div fallback.
//
// This revision: all output stores are NONTEMPORAL (global_store_dwordx4 nt).
// The output (67 MB) is 2x aggregate L2 and is never re-read; regular stores
// allocate L2 lines and churn against the 537 MB of harness poison traffic
// that immediately precedes this kernel in the timed graph. nt streams past
// L2 allocation -> store BW should match fillBuffer's ~6.5 TB/s.

typedef int v4i __attribute__((ext_vector_type(4)));

template <bool POW2>
__global__ __launch_bounds__(256) void DynamicPatcher_62448824484363_kernel(
    int* __restrict__ out,
    int B, int S, int P,
    int avg, int sh,           // sh = log2(avg) when POW2
    int nf, int breakRem, int lastVal,
    int blocksPerRow)
{
    const int row = blockIdx.y;

    if ((int)blockIdx.x == blocksPerRow) {
        // ---- patch_lengths for this row ----
        int* lrow = out + (size_t)row * P;
        for (int i = threadIdx.x * 4; i < P; i += 256 * 4) {
            v4i v;
            #define LVAL(p) ((p) < nf ? avg : ((p) == P - 1 ? lastVal : ((p) == nf ? breakRem : 0)))
            v.x = LVAL(i);
            v.y = LVAL(i + 1);
            v.z = LVAL(i + 2);
            v.w = LVAL(i + 3);
            #undef LVAL
            __builtin_nontemporal_store(v, reinterpret_cast<v4i*>(lrow + i));
        }
        return;
    }

    // ---- patch_ids for this row ----
    int* irow = out + (size_t)B * P + (size_t)row * S;
    const int base = blockIdx.x * 4096 + threadIdx.x * 4;  // element index

    #pragma unroll
    for (int u = 0; u < 4; ++u) {
        int pos = base + u * 1024;
        if (pos >= S) break;           // only the ragged last block ever exits here
        v4i v;
        if (POW2) {
            v.x = min(pos >> sh, nf);
            v.y = min((pos + 1) >> sh, nf);
            v.z = min((pos + 2) >> sh, nf);
            v.w = min((pos + 3) >> sh, nf);
        } else {
            int q = pos / avg;         // wave-uniform-divisor u32 div (rare path)
            int r = pos - q * avg;
            int a2 = avg + avg;
            int a3 = a2 + avg;
            v.x = min(q, nf);
            v.y = min(q + (r + 1 >= avg) + (r + 1 >= a2) + (r + 1 >= a3), nf);
            v.z = min(q + (r + 2 >= avg) + (r + 2 >= a2) + (r + 2 >= a3), nf);
            v.w = min(q + (r + 3 >= avg) + (r + 3 >= a2) + (r + 3 >= a3), nf);
        }
        __builtin_nontemporal_store(v, reinterpret_cast<v4i*>(irow + pos));  // 16 B nt store
    }
}

extern "C" void kernel_launch(void* const* d_in, const int* in_sizes, int n_in,
                              void* d_out, int out_size, void* d_ws, size_t ws_size,
                              hipStream_t stream) {
    (void)d_in; (void)n_in; (void)d_ws; (void)ws_size;

    const int P = 1024;                          // MAX_PATCHES
    long long BS = (long long)in_sizes[0];       // B*S
    long long BPll = (long long)out_size - BS;   // B*P
    int B = (int)(BPll / P);
    int S = (int)(BS / B);

    long long avgll = (long long)S / P;
    if (avgll < 1) avgll = 1;
    int avg = (int)avgll;

    // nf = #iterations p in [0, P-1) with remaining (= S - p*avg) > avg
    long long nfll = 0;
    if (S > avg) {
        nfll = ((long long)S - avg - 1) / avg + 1;
        if (nfll > P - 1) nfll = P - 1;
    }
    int nf = (int)nfll;

    int breakRem = (int)(S - nfll * avg);
    int lastVal;
    if (nf < P - 1) {
        lastVal = breakRem;                      // break leaves 'remaining' unchanged
    } else {
        long long rf = (long long)S - (long long)(P - 1) * avg;
        lastVal = rf > 0 ? (int)rf : 0;
    }

    int blocksPerRow = (S + 4095) / 4096;        // 4096 elements per x-block
    dim3 grid(blocksPerRow + 1, B);

    bool pow2 = (avg & (avg - 1)) == 0;
    int sh = 0;
    if (pow2) { int a = avg; while (a > 1) { a >>= 1; ++sh; } }

    if (pow2) {
        DynamicPatcher_62448824484363_kernel<true><<<grid, 256, 0, stream>>>(
            (int*)d_out, B, S, P, avg, sh, nf, breakRem, lastVal, blocksPerRow);
    } else {
        DynamicPatcher_62448824484363_kernel<false><<<grid, 256, 0, stream>>>(
            (int*)d_out, B, S, P, avg, sh, nf, breakRem, lastVal, blocksPerRow);
    }
}

// Round 2
// 101.780 us; speedup vs baseline: 1.0045x; 1.0045x over previous
//
#include <hip/hip_runtime.h>

// DynamicPatcher: out = [patch_lengths (B,P) int32 | patch_ids (B,S) int32] flat.
// Input entropy is used only for its shape -> pure store kernel, ~67 MB writes.
//
// Closed form (host-side): avg = max(S/P,1); nf = #leading patches of size avg;
// lengths[p<nf]=avg, lengths[nf]=breakRem (if break), lengths[P-1]=lastVal;
// patch_ids[pos] = min(pos/avg, nf).
//
// Layout: gridDim.y = row (batch). x-blocks [0, blocksPerRow) write patch_ids;
// each thread stores UNROLL=8 x int4 = 128 B (u-stride 4 KB inside the block's
// 32 KB span; every store instruction is a wave-contiguous 1 KB burst).
// x-block == blocksPerRow writes the row's patch_lengths.
//
// R1 lesson: nt stores neutral -> L2 churn was not the limiter. This revision
// halves workgroup count (4112 -> 2064) / wave count (16.4K -> 8.3K) to cut
// wave-churn + WG-dispatch ramp, the remaining candidate for the gap between
// the kernel's ~19 us slot and its 10.3 us bytes-floor (67 MB @ 6.5 TB/s).

typedef int v4i __attribute__((ext_vector_type(4)));

#define UNROLL 8   // int4 stores per thread; block span = 256*4*UNROLL elems

template <bool POW2>
__global__ __launch_bounds__(256) void DynamicPatcher_62448824484363_kernel(
    int* __restrict__ out,
    int B, int S, int P,
    int avg, int sh,           // sh = log2(avg) when POW2
    int nf, int breakRem, int lastVal,
    int blocksPerRow)
{
    const int row = blockIdx.y;

    if ((int)blockIdx.x == blocksPerRow) {
        // ---- patch_lengths for this row ----
        int* lrow = out + (size_t)row * P;
        for (int i = threadIdx.x * 4; i < P; i += 256 * 4) {
            v4i v;
            #define LVAL(p) ((p) < nf ? avg : ((p) == P - 1 ? lastVal : ((p) == nf ? breakRem : 0)))
            v.x = LVAL(i);
            v.y = LVAL(i + 1);
            v.z = LVAL(i + 2);
            v.w = LVAL(i + 3);
            #undef LVAL
            __builtin_nontemporal_store(v, reinterpret_cast<v4i*>(lrow + i));
        }
        return;
    }

    // ---- patch_ids for this row ----
    int* irow = out + (size_t)B * P + (size_t)row * S;
    const int span = 256 * 4 * UNROLL;                 // elems per x-block
    const int base = blockIdx.x * span + threadIdx.x * 4;

    #pragma unroll
    for (int u = 0; u < UNROLL; ++u) {
        int pos = base + u * 1024;
        if (pos >= S) break;           // only the ragged last block ever exits here
        v4i v;
        if (POW2) {
            v.x = min(pos >> sh, nf);
            v.y = min((pos + 1) >> sh, nf);
            v.z = min((pos + 2) >> sh, nf);
            v.w = min((pos + 3) >> sh, nf);
        } else {
            int q = pos / avg;         // wave-uniform-divisor u32 div (rare path)
            int r = pos - q * avg;
            int a2 = avg + avg;
            int a3 = a2 + avg;
            v.x = min(q, nf);
            v.y = min(q + (r + 1 >= avg) + (r + 1 >= a2) + (r + 1 >= a3), nf);
            v.z = min(q + (r + 2 >= avg) + (r + 2 >= a2) + (r + 2 >= a3), nf);
            v.w = min(q + (r + 3 >= avg) + (r + 3 >= a2) + (r + 3 >= a3), nf);
        }
        __builtin_nontemporal_store(v, reinterpret_cast<v4i*>(irow + pos));  // 16 B nt store
    }
}

extern "C" void kernel_launch(void* const* d_in, const int* in_sizes, int n_in,
                              void* d_out, int out_size, void* d_ws, size_t ws_size,
                              hipStream_t stream) {
    (void)d_in; (void)n_in; (void)d_ws; (void)ws_size;

    const int P = 1024;                          // MAX_PATCHES
    long long BS = (long long)in_sizes[0];       // B*S
    long long BPll = (long long)out_size - BS;   // B*P
    int B = (int)(BPll / P);
    int S = (int)(BS / B);

    long long avgll = (long long)S / P;
    if (avgll < 1) avgll = 1;
    int avg = (int)avgll;

    // nf = #iterations p in [0, P-1) with remaining (= S - p*avg) > avg
    long long nfll = 0;
    if (S > avg) {
        nfll = ((long long)S - avg - 1) / avg + 1;
        if (nfll > P - 1) nfll = P - 1;
    }
    int nf = (int)nfll;

    int breakRem = (int)(S - nfll * avg);
    int lastVal;
    if (nf < P - 1) {
        lastVal = breakRem;                      // break leaves 'remaining' unchanged
    } else {
        long long rf = (long long)S - (long long)(P - 1) * avg;
        lastVal = rf > 0 ? (int)rf : 0;
    }

    const int span = 256 * 4 * UNROLL;           // 8192 elems per x-block
    int blocksPerRow = (S + span - 1) / span;
    dim3 grid(blocksPerRow + 1, B);

    bool pow2 = (avg & (avg - 1)) == 0;
    int sh = 0;
    if (pow2) { int a = avg; while (a > 1) { a >>= 1; ++sh; } }

    if (pow2) {
        DynamicPatcher_62448824484363_kernel<true><<<grid, 256, 0, stream>>>(
            (int*)d_out, B, S, P, avg, sh, nf, breakRem, lastVal, blocksPerRow);
    } else {
        DynamicPatcher_62448824484363_kernel<false><<<grid, 256, 0, stream>>>(
            (int*)d_out, B, S, P, avg, sh, nf, breakRem, lastVal, blocksPerRow);
    }
}